// Round 12
// baseline (302.993 us; speedup 1.0000x reference)
//
#include <hip/hip_runtime.h>
#include <hip/hip_bf16.h>

// B=8, N=4096, D=H=256. out[b,h] = sum_k w[b,k]*V[b,k,h],
//   w[b,k] = (1/N) sum_q exp(scale*s_qk)/l_q,  l_q = sum_k exp(scale*s_qk)
// R11: score passes get a TRUE 2-deep DMA pipeline:
//   per step: [s_waitcnt vmcnt(0) lgkmcnt(0); raw s_barrier] -> issue DMA(s+1)
//   into the other buffer -> compute(s). The prefetch flies across compute.
//   (R7/R8 failed because __syncthreads' implicit vmcnt(0) drained the
//   prefetch; raw s_barrier has no drain. Wait precedes barrier, so
//   barrier-exit proves all waves' step-s DMAs landed.)
//   Buffer parity = dc&1 (kt*4 even) -> no flat counter, low reg pressure.
// qkv/converts/finalize: R10-verbatim.

#define NTOK 4096
#define HDIM 256
#define NBATCH 8
#define SCALE 0.0625f  // 1/sqrt(256)

typedef __attribute__((ext_vector_type(8))) short short8_t;   // 8 bf16 (4 VGPRs)
typedef __attribute__((ext_vector_type(16))) float f32x16;    // 32x32 C/D frag

__device__ __forceinline__ unsigned short f2bf(float f) {
    unsigned u = __float_as_uint(f);
    u += 0x7fff + ((u >> 16) & 1);   // RNE
    return (unsigned short)(u >> 16);
}

#define MFMA(a, b, c) __builtin_amdgcn_mfma_f32_32x32x16_bf16(a, b, c, 0, 0, 0)

// wait own DMAs + LDS ops, then raw barrier (NO implicit drain after).
#define PIPE_BARRIER() do { \
    asm volatile("s_waitcnt vmcnt(0) lgkmcnt(0)" ::: "memory"); \
    asm volatile("s_barrier" ::: "memory"); \
} while (0)

__device__ __forceinline__ void async_cp16(const void* g, void* l) {
    __builtin_amdgcn_global_load_lds((const __attribute__((address_space(1))) void*)g,
                                     (__attribute__((address_space(3))) void*)l, 16, 0, 0);
}

// Stage 128 rows x 64 bf16 cols into swizzled LDS: 16B unit (r,u) -> r*8 + (u^(r&7)).
__device__ __forceinline__ void stage_swz(unsigned short* lds, const unsigned short* src,
                                          int row0, int dbase, int w, int l) {
#pragma unroll
    for (int i = 0; i < 4; ++i) {
        int rloc = w * 32 + i * 8 + (l >> 3);
        int u = (l & 7) ^ (l >> 3);
        const unsigned short* g = src + (size_t)(row0 + rloc) * HDIM + dbase + u * 8;
        unsigned short* d = lds + (w * 32 + i * 8) * 64;
        async_cp16(g, d);
    }
}

__device__ __forceinline__ short8_t frd(const unsigned short* lds, int rb, int lo, int u) {
    return *(const short8_t*)(lds + ((rb * 32 + lo) * 8 + (u ^ (lo & 7))) * 8);
}

__global__ void zero_kernel(float* __restrict__ w, float* __restrict__ l, float* __restrict__ out) {
    int i = blockIdx.x * 256 + threadIdx.x;
    w[i] = 0.f;
    l[i] = 0.f;
    if (i < NBATCH * HDIM) out[i] = 0.f;
}

__global__ void convert_x(const float* __restrict__ x, unsigned short* __restrict__ xbf) {
    int i = (blockIdx.x * 256 + threadIdx.x) * 4;
    float4 v = *(const float4*)(x + i);
    ushort4 o;
    o.x = f2bf(v.x); o.y = f2bf(v.y); o.z = f2bf(v.z); o.w = f2bf(v.w);
    *(ushort4*)(xbf + i) = o;
}

__global__ void convert_wt(const float* __restrict__ Wq, const float* __restrict__ Wk,
                           const float* __restrict__ Wv, unsigned short* __restrict__ Wt) {
    int z = blockIdx.y;
    const float* W = (z == 0) ? Wq : (z == 1) ? Wk : Wv;
    unsigned short* o = Wt + z * 65536;
    int n = threadIdx.x;
    for (int kk = 0; kk < 32; ++kk) {
        int k = blockIdx.x * 32 + kk;
        o[n * 256 + k] = f2bf(W[k * 256 + n]);
    }
}

// ---------------- QKV projection (R10-verbatim) ----------------
__global__ __launch_bounds__(256) void qkv_mfma(const unsigned short* __restrict__ xbf,
                                                const unsigned short* __restrict__ Wt,
                                                const float* __restrict__ bq, const float* __restrict__ bk,
                                                const float* __restrict__ bv,
                                                unsigned short* __restrict__ Qbf,
                                                unsigned short* __restrict__ Kbf,
                                                float* __restrict__ Vf) {
    const int z = blockIdx.z;
    const unsigned short* Wz = Wt + z * 65536;
    const float* bias = (z == 0) ? bq : (z == 1) ? bk : bv;
    const int m0 = blockIdx.x * 128, n0 = blockIdx.y * 128;
    const int t = threadIdx.x, w = t >> 6, l = t & 63, lo = l & 31, hi = l >> 5;
    const int rm = (w & 1) * 2, rn = (w >> 1) * 2;

    __shared__ __align__(16) char smem[32768];
    unsigned short* Xb = (unsigned short*)smem;
    unsigned short* Wb = (unsigned short*)(smem + 16384);

    f32x16 acc[2][2];
#pragma unroll
    for (int a = 0; a < 2; ++a)
#pragma unroll
        for (int c = 0; c < 2; ++c)
#pragma unroll
            for (int r = 0; r < 16; ++r) acc[a][c][r] = 0.f;

    for (int dc = 0; dc < 4; ++dc) {
        __syncthreads();
        stage_swz(Xb, xbf, m0, dc * 64, w, l);
        stage_swz(Wb, Wz, n0, dc * 64, w, l);
        __syncthreads();
#pragma unroll
        for (int ks = 0; ks < 4; ++ks) {
            int u = ks * 2 + hi;
            short8_t a0 = frd(Xb, rm + 0, lo, u);
            short8_t a1 = frd(Xb, rm + 1, lo, u);
            short8_t b0 = frd(Wb, rn + 0, lo, u);
            short8_t b1 = frd(Wb, rn + 1, lo, u);
            acc[0][0] = MFMA(a0, b0, acc[0][0]);
            acc[0][1] = MFMA(a0, b1, acc[0][1]);
            acc[1][0] = MFMA(a1, b0, acc[1][0]);
            acc[1][1] = MFMA(a1, b1, acc[1][1]);
        }
    }
    float bc0 = bias[n0 + (w >> 1) * 64 + lo];
    float bc1 = bias[n0 + (w >> 1) * 64 + 32 + lo];
#pragma unroll
    for (int mb = 0; mb < 2; ++mb)
#pragma unroll
        for (int r = 0; r < 16; ++r) {
            int row = m0 + (w & 1) * 64 + mb * 32 + (r & 3) + 8 * (r >> 2) + 4 * hi;
            int c0 = n0 + (w >> 1) * 64 + lo, c1 = c0 + 32;
            float v0 = acc[mb][0][r] + bc0;
            float v1 = acc[mb][1][r] + bc1;
            if (z == 2) {
                Vf[(size_t)row * HDIM + c0] = v0;
                Vf[(size_t)row * HDIM + c1] = v1;
            } else {
                unsigned short* o = (z == 0) ? Qbf : Kbf;
                o[(size_t)row * HDIM + c0] = f2bf(v0);
                o[(size_t)row * HDIM + c1] = f2bf(v1);
            }
        }
}

// ---------------- pass 1: l[b,q] = sum_k exp(scale*s), pipelined ----------------
__global__ __launch_bounds__(256) void score_pass1(const unsigned short* __restrict__ Qbf,
                                                   const unsigned short* __restrict__ Kbf,
                                                   float* __restrict__ lsum) {
    const int b = blockIdx.z;
    const int q0 = blockIdx.x * 128;
    const int kbase = blockIdx.y * 512;
    const int t = threadIdx.x, w = t >> 6, l = t & 63, lo = l & 31, hi = l >> 5;
    const int rq = (w & 1) * 2, rk = (w >> 1) * 2;
    const unsigned short* Qb = Qbf + (size_t)b * NTOK * HDIM;
    const unsigned short* Kb = Kbf + (size_t)b * NTOK * HDIM;

    __shared__ __align__(16) char smem[65536];   // Q0|Q1|K0|K1, 16KB each; red overlays
    float* red = (float*)smem;

    float rs[2][16];
#pragma unroll
    for (int mb = 0; mb < 2; ++mb)
#pragma unroll
        for (int r = 0; r < 16; ++r) rs[mb][r] = 0.f;

    f32x16 acc[2][2];

    stage_swz((unsigned short*)smem, Qb, q0, 0, w, l);
    stage_swz((unsigned short*)(smem + 32768), Kb, kbase, 0, w, l);

    for (int kt = 0; kt < 4; ++kt) {
#pragma unroll
        for (int dc = 0; dc < 4; ++dc) {
            PIPE_BARRIER();   // own DMAs for step s done; all waves joined
            if (dc == 0) {
#pragma unroll
                for (int a = 0; a < 2; ++a)
#pragma unroll
                    for (int c = 0; c < 2; ++c)
#pragma unroll
                        for (int r = 0; r < 16; ++r) acc[a][c][r] = 0.f;
            }
            if (kt * 4 + dc < 15) {   // prefetch step s+1 into the other buffer
                const int ndc = (dc + 1) & 3;
                const int nkt = kt + (dc == 3);
                stage_swz((unsigned short*)(smem + (ndc & 1) * 16384), Qb, q0, ndc * 64, w, l);
                stage_swz((unsigned short*)(smem + 32768 + (ndc & 1) * 16384), Kb,
                          kbase + nkt * 128, ndc * 64, w, l);
            }
            const unsigned short* Qs = (const unsigned short*)(smem + (dc & 1) * 16384);
            const unsigned short* Ks = (const unsigned short*)(smem + 32768 + (dc & 1) * 16384);
#pragma unroll
            for (int ks = 0; ks < 4; ++ks) {
                int u = ks * 2 + hi;
                short8_t a0 = frd(Qs, rq + 0, lo, u);
                short8_t a1 = frd(Qs, rq + 1, lo, u);
                short8_t b0 = frd(Ks, rk + 0, lo, u);
                short8_t b1 = frd(Ks, rk + 1, lo, u);
                acc[0][0] = MFMA(a0, b0, acc[0][0]);
                acc[0][1] = MFMA(a0, b1, acc[0][1]);
                acc[1][0] = MFMA(a1, b0, acc[1][0]);
                acc[1][1] = MFMA(a1, b1, acc[1][1]);
            }
            if (dc == 3) {
#pragma unroll
                for (int mb = 0; mb < 2; ++mb)
#pragma unroll
                    for (int r = 0; r < 16; ++r)
                        rs[mb][r] += __expf(acc[mb][0][r] * SCALE) + __expf(acc[mb][1][r] * SCALE);
            }
        }
    }
    __syncthreads();
#pragma unroll
    for (int mb = 0; mb < 2; ++mb)
#pragma unroll
        for (int r = 0; r < 16; ++r) {
            int row = (w & 1) * 64 + mb * 32 + (r & 3) + 8 * (r >> 2) + 4 * hi;
            red[row * 66 + (w >> 1) * 32 + lo] = rs[mb][r];
        }
    __syncthreads();
    if (t < 128) {
        float s = 0.f;
#pragma unroll 8
        for (int j = 0; j < 64; ++j) s += red[t * 66 + j];
        atomicAdd(&lsum[b * NTOK + q0 + t], s);
    }
}

// ---------------- pass 2: w[b,k] += sum_q exp(scale*s)/l_q, pipelined ----------------
__global__ __launch_bounds__(256) void score_pass2(const unsigned short* __restrict__ Qbf,
                                                   const unsigned short* __restrict__ Kbf,
                                                   const float* __restrict__ lsum,
                                                   float* __restrict__ wsum) {
    const int b = blockIdx.z;
    const int k0 = blockIdx.x * 128;
    const int qbase = blockIdx.y * 512;
    const int t = threadIdx.x, w = t >> 6, l = t & 63, lo = l & 31, hi = l >> 5;
    const int rq = (w & 1) * 2, rk = (w >> 1) * 2;
    const unsigned short* Qb = Qbf + (size_t)b * NTOK * HDIM;
    const unsigned short* Kb = Kbf + (size_t)b * NTOK * HDIM;

    __shared__ __align__(16) char smem[65536];
    __shared__ float linv_s[2][128];
    float* red2 = (float*)smem;

    float cs0 = 0.f, cs1 = 0.f;
    f32x16 acc[2][2];

    stage_swz((unsigned short*)smem, Qb, qbase, 0, w, l);
    stage_swz((unsigned short*)(smem + 32768), Kb, k0, 0, w, l);
    if (t < 128) linv_s[0][t] = 1.0f / lsum[b * NTOK + qbase + t];

    for (int kt = 0; kt < 4; ++kt) {
#pragma unroll
        for (int dc = 0; dc < 4; ++dc) {
            PIPE_BARRIER();
            if (dc == 0) {
#pragma unroll
                for (int a = 0; a < 2; ++a)
#pragma unroll
                    for (int c = 0; c < 2; ++c)
#pragma unroll
                        for (int r = 0; r < 16; ++r) acc[a][c][r] = 0.f;
            }
            if (kt * 4 + dc < 15) {
                const int ndc = (dc + 1) & 3;
                const int nkt = kt + (dc == 3);
                stage_swz((unsigned short*)(smem + (ndc & 1) * 16384), Qb,
                          qbase + nkt * 128, ndc * 64, w, l);
                stage_swz((unsigned short*)(smem + 32768 + (ndc & 1) * 16384), Kb,
                          k0, ndc * 64, w, l);
                if (ndc == 0 && t < 128)   // next q-tile's 1/l into ping-pong slot
                    linv_s[nkt & 1][t] = 1.0f / lsum[b * NTOK + qbase + nkt * 128 + t];
            }
            const unsigned short* Qs = (const unsigned short*)(smem + (dc & 1) * 16384);
            const unsigned short* Ks = (const unsigned short*)(smem + 32768 + (dc & 1) * 16384);
#pragma unroll
            for (int ks = 0; ks < 4; ++ks) {
                int u = ks * 2 + hi;
                short8_t a0 = frd(Qs, rq + 0, lo, u);
                short8_t a1 = frd(Qs, rq + 1, lo, u);
                short8_t b0 = frd(Ks, rk + 0, lo, u);
                short8_t b1 = frd(Ks, rk + 1, lo, u);
                acc[0][0] = MFMA(a0, b0, acc[0][0]);
                acc[0][1] = MFMA(a0, b1, acc[0][1]);
                acc[1][0] = MFMA(a1, b0, acc[1][0]);
                acc[1][1] = MFMA(a1, b1, acc[1][1]);
            }
            if (dc == 3) {
#pragma unroll
                for (int mb = 0; mb < 2; ++mb)
#pragma unroll
                    for (int r = 0; r < 16; ++r) {
                        float li = linv_s[kt & 1][(w & 1) * 64 + mb * 32 + (r & 3) + 8 * (r >> 2) + 4 * hi];
                        cs0 += __expf(acc[mb][0][r] * SCALE) * li;
                        cs1 += __expf(acc[mb][1][r] * SCALE) * li;
                    }
            }
        }
    }
    __syncthreads();
    red2[((w >> 1) * 64 + lo) * 5 + (w & 1) * 2 + hi] = cs0;
    red2[((w >> 1) * 64 + 32 + lo) * 5 + (w & 1) * 2 + hi] = cs1;
    __syncthreads();
    if (t < 128) {
        float s = red2[t * 5 + 0] + red2[t * 5 + 1] + red2[t * 5 + 2] + red2[t * 5 + 3];
        atomicAdd(&wsum[b * NTOK + k0 + t], s);
    }
}

__global__ __launch_bounds__(256) void finalize_kernel(const float* __restrict__ V,
                                                       const float* __restrict__ w,
                                                       float* __restrict__ out) {
    const int b = blockIdx.y;
    const int k0 = blockIdx.x * 256;
    const int h = threadIdx.x;
    __shared__ float wsh[256];
    wsh[h] = w[b * NTOK + k0 + h];
    __syncthreads();
    const float* Vb = V + ((size_t)b * NTOK + k0) * HDIM;
    float acc = 0.f;
#pragma unroll 4
    for (int kk = 0; kk < 256; ++kk) acc = fmaf(wsh[kk], Vb[(size_t)kk * HDIM + h], acc);
    atomicAdd(&out[b * HDIM + h], acc * (1.0f / (float)NTOK));
}

extern "C" void kernel_launch(void* const* d_in, const int* in_sizes, int n_in,
                              void* d_out, int out_size, void* d_ws, size_t ws_size,
                              hipStream_t stream) {
    const float* x  = (const float*)d_in[0];
    const float* Wq = (const float*)d_in[1];
    const float* bq = (const float*)d_in[2];
    const float* Wk = (const float*)d_in[3];
    const float* bk = (const float*)d_in[4];
    const float* Wv = (const float*)d_in[5];
    const float* bv = (const float*)d_in[6];
    float* out = (float*)d_out;

    const size_t BNH = (size_t)NBATCH * NTOK * HDIM;   // 8388608
    unsigned short* Wt  = (unsigned short*)d_ws;        // 3 transposed bf16 weights
    unsigned short* xbf = Wt + 3 * 65536;               // bf16 x
    unsigned short* Qbf = xbf + BNH;
    unsigned short* Kbf = Qbf + BNH;
    float* Vf   = (float*)(Kbf + BNH);                  // fp32 V
    float* lsum = Vf + BNH;
    float* wsum = lsum + (size_t)NBATCH * NTOK;

    zero_kernel<<<dim3(128), dim3(256), 0, stream>>>(wsum, lsum, out);
    convert_x<<<dim3(8192), dim3(256), 0, stream>>>(x, xbf);
    convert_wt<<<dim3(8, 3), dim3(256), 0, stream>>>(Wq, Wk, Wv, Wt);
    qkv_mfma<<<dim3(256, 2, 3), dim3(256), 0, stream>>>(xbf, Wt, bq, bk, bv, Qbf, Kbf, Vf);
    score_pass1<<<dim3(32, 8, 8), dim3(256), 0, stream>>>(Qbf, Kbf, lsum);
    score_pass2<<<dim3(32, 8, 8), dim3(256), 0, stream>>>(Qbf, Kbf, lsum, wsum);
    finalize_kernel<<<dim3(16, 8), dim3(256), 0, stream>>>(Vf, wsum, out);
}